// Round 3
// baseline (275.469 us; speedup 1.0000x reference)
//
#include <hip/hip_runtime.h>
#include <hip/hip_bf16.h>

// Problem constants (fixed by the reference)
#define NROWS   200000
#define DSP     64      // spatial width
#define DST     131     // structural width
#define DOUT    256
#define K1PAD   224     // 195 padded to 7*32
#define K2PAD   160     // 131 padded to 5*32
#define NK1     7
#define NK2     5
#define BM      32      // rows per block (32 -> 25.6KB LDS -> 6 blocks/CU)
#define NBLK    (NROWS / BM)   // 6250 exactly
#define LD1     (K1PAD + 8)    // 232 shorts = 464 B row stride (16B-aligned)
#define LD2     (K2PAD + 8)    // 168 shorts = 336 B row stride (16B-aligned)

typedef short bf8   __attribute__((ext_vector_type(8)));   // 8 bf16 (4 VGPRs)
typedef float f32x4 __attribute__((ext_vector_type(4)));

// f32 -> bf16 (RNE) on raw bits
__device__ __forceinline__ unsigned short f2bf(float x) {
    unsigned u = __float_as_uint(x);
    unsigned r = (u + 0x7fffu + ((u >> 16) & 1u)) >> 16;
    return (unsigned short)r;
}
__device__ __forceinline__ unsigned pack2(unsigned short lo, unsigned short hi) {
    return (unsigned)lo | ((unsigned)hi << 16);
}

// ---------------------------------------------------------------------------
// Pack weights into MFMA B-fragment order:
//   entry(ks, cb, lane, j) = W[n][k], n = cb*16 + (lane&15), k = ks*32 + (lane>>4)*8 + j
// ---------------------------------------------------------------------------
__global__ __launch_bounds__(256) void wprep(const float* __restrict__ Wc,
                                             const float* __restrict__ Wa,
                                             short* __restrict__ w1p,
                                             short* __restrict__ w2p) {
    int idx = blockIdx.x * 256 + threadIdx.x;
    if (idx < 57344) {
        int j  = idx & 7;
        int l  = (idx >> 3) & 63;
        int cb = (idx >> 9) & 15;
        int ks = idx >> 13;
        int k  = ks * 32 + (l >> 4) * 8 + j;
        int n  = cb * 16 + (l & 15);
        float v = (k < 195) ? Wc[n * 195 + k] : 0.0f;
        w1p[idx] = (short)f2bf(v);
    } else {
        int id2 = idx - 57344;
        if (id2 < 40960) {
            int j  = id2 & 7;
            int l  = (id2 >> 3) & 63;
            int cb = (id2 >> 9) & 15;
            int ks = id2 >> 13;
            int k  = ks * 32 + (l >> 4) * 8 + j;
            int n  = cb * 16 + (l & 15);
            float v = (k < 131) ? Wa[n * 131 + k] : 0.0f;
            w2p[id2] = (short)f2bf(v);
        }
    }
}

// ---------------------------------------------------------------------------
// MFMA core: LDS A-tile [BM][LDPAD] (bf16), fragment-packed B in wp,
// computes the BMx256 tile and stores f32 + bias. MREP = BM/16.
// ---------------------------------------------------------------------------
template <int NK, int LDPAD, int MREP>
__device__ __forceinline__ void mfma_tile_and_store(
        const short (*lds)[LDPAD],
        const short* __restrict__ wp,
        const float* __restrict__ bias,
        float* __restrict__ out,
        int r0, int t) {
    const int wave = t >> 6;
    const int l    = t & 63;
    const int lr   = l & 15;   // A-row / D-col
    const int lk   = l >> 4;   // k-group / D-row-group

    f32x4 acc[MREP][4];
    #pragma unroll
    for (int m = 0; m < MREP; ++m)
        #pragma unroll
        for (int n = 0; n < 4; ++n)
            acc[m][n] = (f32x4){0.f, 0.f, 0.f, 0.f};

    #pragma unroll
    for (int ks = 0; ks < NK; ++ks) {
        bf8 a[MREP], bb[4];
        #pragma unroll
        for (int m = 0; m < MREP; ++m)
            a[m] = *(const bf8*)&lds[m * 16 + lr][ks * 32 + lk * 8];
        #pragma unroll
        for (int n = 0; n < 4; ++n) {
            int cb = wave * 4 + n;
            bb[n] = *(const bf8*)(wp + (((ks * 16 + cb) * 64 + l) << 3));
        }
        #pragma unroll
        for (int m = 0; m < MREP; ++m)
            #pragma unroll
            for (int n = 0; n < 4; ++n)
                acc[m][n] = __builtin_amdgcn_mfma_f32_16x16x32_bf16(
                                a[m], bb[n], acc[m][n], 0, 0, 0);
    }

    #pragma unroll
    for (int n = 0; n < 4; ++n) {
        int col = wave * 64 + n * 16 + lr;
        float bv = bias[col];
        #pragma unroll
        for (int m = 0; m < MREP; ++m) {
            #pragma unroll
            for (int r = 0; r < 4; ++r) {
                int row = m * 16 + lk * 4 + r;
                out[(size_t)(r0 + row) * DOUT + col] = acc[m][n][r] + bv;
            }
        }
    }
}

// ---------------------------------------------------------------------------
// Fused kernel, BM=32: whole-wave-per-row staging for maximal gather ILP.
// Each wave stages 8 rows: cols {l, l+64, tail(128..130)} of self + 3 gathered
// rows, producing lds1 (A1: [spatial|structural]) and lds2 (A2: agg) in one
// pass over the data. Pad cols written by lanes 3..31 in the same loop.
// ---------------------------------------------------------------------------
__global__ __launch_bounds__(256, 6) void fused(
        const float* __restrict__ spatial,
        const float* __restrict__ structural,
        const int*   __restrict__ neigh,
        const short* __restrict__ w1p,
        const short* __restrict__ w2p,
        const float* __restrict__ b_comb,
        const float* __restrict__ b_agg,
        float* __restrict__ out1,
        float* __restrict__ out2) {
    __shared__ short lds1[BM][LD1];
    __shared__ short lds2[BM][LD2];
    const int t    = threadIdx.x;
    const int wave = t >> 6;
    const int l    = t & 63;
    const int r0   = blockIdx.x * BM;

    // ---- stage spatial -> lds1 cols 0..63 (float4 loads, 8B LDS writes) ----
    {
        int h  = t & 15;             // 16 float4-slots per row
        int sl = t >> 4;             // 16 rows per pass
        #pragma unroll
        for (int p = 0; p < 2; ++p) {
            int row = sl + 16 * p;
            float4 v = *(const float4*)(spatial + (size_t)(r0 + row) * DSP + 4 * h);
            uint2 w;
            w.x = pack2(f2bf(v.x), f2bf(v.y));
            w.y = pack2(f2bf(v.z), f2bf(v.w));
            *(uint2*)&lds1[row][4 * h] = w;
        }
    }

    // ---- structural self -> lds1 cols 64..194 (+pad), agg -> lds2 (+pad) ----
    {
        const int rowb = wave * 8;
        #pragma unroll 4
        for (int rr = 0; rr < 8; ++rr) {
            int row = rowb + rr;
            size_t r = (size_t)(r0 + row);
            const float* s0 = structural + r * DST;
            int n0 = neigh[r * 3 + 0];
            int n1 = neigh[r * 3 + 1];
            int n2 = neigh[r * 3 + 2];
            const float* p1 = structural + (size_t)n0 * DST;
            const float* p2 = structural + (size_t)n1 * DST;
            const float* p3 = structural + (size_t)n2 * DST;

            // cols l and l+64: fully-coalesced 256B segments per pointer
            float a0 = s0[l],      b0 = p1[l],      c0 = p2[l],      d0 = p3[l];
            float a1 = s0[l + 64], b1 = p1[l + 64], c1 = p2[l + 64], d1 = p3[l + 64];
            lds1[row][64 + l]  = (short)f2bf(a0);
            lds1[row][128 + l] = (short)f2bf(a1);
            lds2[row][l]       = (short)f2bf((a0 + b0 + c0 + d0) * 0.25f);
            lds2[row][64 + l]  = (short)f2bf((a1 + b1 + c1 + d1) * 0.25f);

            if (l < 3) {                    // data tail: cols 128..130
                float a2 = s0[128 + l], b2 = p1[128 + l],
                      c2 = p2[128 + l], d2 = p3[128 + l];
                lds1[row][192 + l] = (short)f2bf(a2);
                lds2[row][128 + l] = (short)f2bf((a2 + b2 + c2 + d2) * 0.25f);
            } else if (l < 32) {            // zero pad: lds1 195..223, lds2 131..159
                lds1[row][192 + l] = 0;
                lds2[row][128 + l] = 0;
            }
        }
    }
    __syncthreads();

    mfma_tile_and_store<NK1, LD1, BM / 16>(lds1, w1p, b_comb, out1, r0, t);
    mfma_tile_and_store<NK2, LD2, BM / 16>(lds2, w2p, b_agg, out2, r0, t);
}

// ---------------------------------------------------------------------------
extern "C" void kernel_launch(void* const* d_in, const int* in_sizes, int n_in,
                              void* d_out, int out_size, void* d_ws, size_t ws_size,
                              hipStream_t stream) {
    const float* spatial    = (const float*)d_in[0];
    const float* structural = (const float*)d_in[1];
    const int*   neighbour  = (const int*)  d_in[2];
    const float* W_agg      = (const float*)d_in[3];
    const float* b_agg      = (const float*)d_in[4];
    const float* W_comb     = (const float*)d_in[5];
    const float* b_comb     = (const float*)d_in[6];

    float* out1 = (float*)d_out;
    float* out2 = out1 + (size_t)NROWS * DOUT;

    short* w1p = (short*)d_ws;          // 57344 shorts
    short* w2p = w1p + 57344;           // 40960 shorts

    wprep<<<384, 256, 0, stream>>>(W_comb, W_agg, w1p, w2p);
    fused<<<NBLK, 256, 0, stream>>>(spatial, structural, neighbour,
                                    w1p, w2p, b_comb, b_agg, out1, out2);
}

// Round 4
// 213.356 us; speedup vs baseline: 1.2911x; 1.2911x over previous
//
#include <hip/hip_runtime.h>
#include <hip/hip_bf16.h>

// Problem constants (fixed by the reference)
#define NROWS   200000
#define DSP     64      // spatial width
#define DST     131     // structural width
#define DOUT    256
#define K1PAD   224     // 195 padded to 7*32
#define K2PAD   160     // 131 padded to 5*32
#define NK1     7
#define NK2     5
#define BM      64      // rows per block
#define NBLK    (NROWS / BM)   // 3125 exactly
#define LD1     (K1PAD + 8)    // 232 shorts = 464 B row stride
#define LD2     (K2PAD + 8)    // 168 shorts = 336 B row stride

typedef short bf8   __attribute__((ext_vector_type(8)));   // 8 bf16 (4 VGPRs)
typedef float f32x4 __attribute__((ext_vector_type(4)));

// f32 -> bf16 (RNE) on raw bits (cold path / wprep only)
__device__ __forceinline__ unsigned short f2bf(float x) {
    unsigned u = __float_as_uint(x);
    unsigned r = (u + 0x7fffu + ((u >> 16) & 1u)) >> 16;
    return (unsigned short)r;
}

// hot path: HW bf16 convert
__device__ __forceinline__ unsigned short bf1(float x) {
    __hip_bfloat16 h = __float2bfloat16(x);
    return *reinterpret_cast<unsigned short*>(&h);
}
__device__ __forceinline__ unsigned packbf2(float a, float b) {
    return (unsigned)bf1(a) | ((unsigned)bf1(b) << 16);
}

// ---------------------------------------------------------------------------
// Pack weights into MFMA B-fragment order:
//   entry(ks, cb, lane, j) = W[n][k], n = cb*16 + (lane&15), k = ks*32 + (lane>>4)*8 + j
// ---------------------------------------------------------------------------
__global__ __launch_bounds__(256) void wprep(const float* __restrict__ Wc,
                                             const float* __restrict__ Wa,
                                             short* __restrict__ w1p,
                                             short* __restrict__ w2p) {
    int idx = blockIdx.x * 256 + threadIdx.x;
    if (idx < 57344) {
        int j  = idx & 7;
        int l  = (idx >> 3) & 63;
        int cb = (idx >> 9) & 15;
        int ks = idx >> 13;
        int k  = ks * 32 + (l >> 4) * 8 + j;
        int n  = cb * 16 + (l & 15);
        float v = (k < 195) ? Wc[n * 195 + k] : 0.0f;
        w1p[idx] = (short)f2bf(v);
    } else {
        int id2 = idx - 57344;
        if (id2 < 40960) {
            int j  = id2 & 7;
            int l  = (id2 >> 3) & 63;
            int cb = (id2 >> 9) & 15;
            int ks = id2 >> 13;
            int k  = ks * 32 + (l >> 4) * 8 + j;
            int n  = cb * 16 + (l & 15);
            float v = (k < 131) ? Wa[n * 131 + k] : 0.0f;
            w2p[id2] = (short)f2bf(v);
        }
    }
}

// ---------------------------------------------------------------------------
// MFMA core: LDS A-tile [BM][LDPAD] (bf16), fragment-packed B in wp,
// computes the BMx256 tile and stores f32 + bias. MREP = BM/16.
// ---------------------------------------------------------------------------
template <int NK, int LDPAD, int MREP>
__device__ __forceinline__ void mfma_tile_and_store(
        const short (*lds)[LDPAD],
        const short* __restrict__ wp,
        const float* __restrict__ bias,
        float* __restrict__ out,
        int r0, int t) {
    const int wave = t >> 6;
    const int l    = t & 63;
    const int lr   = l & 15;   // A-row / D-col
    const int lk   = l >> 4;   // k-group / D-row-group

    f32x4 acc[MREP][4];
    #pragma unroll
    for (int m = 0; m < MREP; ++m)
        #pragma unroll
        for (int n = 0; n < 4; ++n)
            acc[m][n] = (f32x4){0.f, 0.f, 0.f, 0.f};

    #pragma unroll
    for (int ks = 0; ks < NK; ++ks) {
        bf8 a[MREP], bb[4];
        #pragma unroll
        for (int m = 0; m < MREP; ++m)
            a[m] = *(const bf8*)&lds[m * 16 + lr][ks * 32 + lk * 8];
        #pragma unroll
        for (int n = 0; n < 4; ++n) {
            int cb = wave * 4 + n;
            bb[n] = *(const bf8*)(wp + (((ks * 16 + cb) * 64 + l) << 3));
        }
        #pragma unroll
        for (int m = 0; m < MREP; ++m)
            #pragma unroll
            for (int n = 0; n < 4; ++n)
                acc[m][n] = __builtin_amdgcn_mfma_f32_16x16x32_bf16(
                                a[m], bb[n], acc[m][n], 0, 0, 0);
    }

    #pragma unroll
    for (int n = 0; n < 4; ++n) {
        int col = wave * 64 + n * 16 + lr;
        float bv = bias[col];
        #pragma unroll
        for (int m = 0; m < MREP; ++m) {
            #pragma unroll
            for (int r = 0; r < 4; ++r) {
                int row = m * 16 + lk * 4 + r;
                out[(size_t)(r0 + row) * DOUT + col] = acc[m][n][r] + bv;
            }
        }
    }
}

// ---------------------------------------------------------------------------
// Fused kernel, BM=64. Staging is dwordx4-based:
//  - wave w owns rows w*16 .. w*16+15
//  - lanes 0..47 preload the wave's 48 neigh indices (one load), broadcast
//    per pass via __shfl (no LDS, no extra barrier)
//  - per pass (2 rows per wave, 8 passes): each half-wave lane owns one 16B
//    column chunk and loads self + 3 neighbour rows itself (4 independent
//    dwordx4), sums in-register, writes 8B to lds1 (self) and lds2 (agg)
//  - tail cols 128..130 via overlapping dword-aligned dwordx4 (sub==31 lanes)
// ---------------------------------------------------------------------------
__global__ __launch_bounds__(256, 3) void fused(
        const float* __restrict__ spatial,
        const float* __restrict__ structural,
        const int*   __restrict__ neigh,
        const short* __restrict__ w1p,
        const short* __restrict__ w2p,
        const float* __restrict__ b_comb,
        const float* __restrict__ b_agg,
        float* __restrict__ out1,
        float* __restrict__ out2) {
    __shared__ short lds1[BM][LD1];
    __shared__ short lds2[BM][LD2];
    const int t  = threadIdx.x;
    const int w  = t >> 6;
    const int l  = t & 63;
    const int r0 = blockIdx.x * BM;

    // ---- per-wave neigh preload: lanes 0..47 hold 16 rows x 3 indices ----
    int nv = 0;
    if (l < 48) {
        int lrow = l / 3;                 // 0..15 (local row)
        int lq   = l - lrow * 3;          // 0..2
        nv = neigh[(r0 + w * 16 + lrow) * 3 + lq];
    }

    // ---- zero pads (per-wave rows; DS program order protects overwrites) ----
    {
        int row = w * 16 + (l >> 2);
        int k   = l & 3;
        *(uint4*)&lds1[row][192 + 8 * k] = make_uint4(0, 0, 0, 0);  // cols 192..223
        *(uint4*)&lds2[row][128 + 8 * k] = make_uint4(0, 0, 0, 0);  // cols 128..159
    }

    // ---- stage spatial -> lds1 cols 0..63 ----
    {
        int h  = t & 15;
        int sl = t >> 4;
        #pragma unroll
        for (int p = 0; p < 4; ++p) {
            int row = sl + 16 * p;
            float4 v = *(const float4*)(spatial + (size_t)(r0 + row) * DSP + 4 * h);
            uint2 wv;
            wv.x = packbf2(v.x, v.y);
            wv.y = packbf2(v.z, v.w);
            *(uint2*)&lds1[row][4 * h] = wv;
        }
    }

    // ---- gather staging ----
    {
        const char* sbase = (const char*)structural;
        const int h   = l >> 5;           // row half
        const int sub = l & 31;           // 16B chunk index (cols 4*sub..4*sub+3)
        #pragma unroll
        for (int p = 0; p < 8; ++p) {
            int local = 2 * p + h;        // 0..15
            int row   = w * 16 + local;
            int srow  = r0 + row;
            int n0 = __shfl(nv, 3 * local + 0);
            int n1 = __shfl(nv, 3 * local + 1);
            int n2 = __shfl(nv, 3 * local + 2);

            unsigned co = 16u * (unsigned)sub;
            float4 v0 = *(const float4*)(sbase + (unsigned)srow * 524u + co);
            float4 v1 = *(const float4*)(sbase + (unsigned)n0   * 524u + co);
            float4 v2 = *(const float4*)(sbase + (unsigned)n1   * 524u + co);
            float4 v3 = *(const float4*)(sbase + (unsigned)n2   * 524u + co);

            // lds1 self: cols 64+4*sub .. 64+4*sub+3
            uint2 wa;
            wa.x = packbf2(v0.x, v0.y);
            wa.y = packbf2(v0.z, v0.w);
            *(uint2*)&lds1[row][64 + 4 * sub] = wa;

            // lds2 agg
            float sx = (v0.x + v1.x + v2.x + v3.x) * 0.25f;
            float sy = (v0.y + v1.y + v2.y + v3.y) * 0.25f;
            float sz = (v0.z + v1.z + v2.z + v3.z) * 0.25f;
            float sw = (v0.w + v1.w + v2.w + v3.w) * 0.25f;
            uint2 wb;
            wb.x = packbf2(sx, sy);
            wb.y = packbf2(sz, sw);
            *(uint2*)&lds2[row][4 * sub] = wb;

            if (sub == 31) {
                // tail: structural cols 128..130 (overlapping load at col 127)
                unsigned to = 508u;   // byte offset of col 127
                float4 t0 = *(const float4*)(sbase + (unsigned)srow * 524u + to);
                float4 t1 = *(const float4*)(sbase + (unsigned)n0   * 524u + to);
                float4 t2 = *(const float4*)(sbase + (unsigned)n1   * 524u + to);
                float4 t3 = *(const float4*)(sbase + (unsigned)n2   * 524u + to);
                // lds1: cols 192..194  (y,z,w = cols 128,129,130)
                *(unsigned*)&lds1[row][192] = packbf2(t0.y, t0.z);
                lds1[row][194] = (short)bf1(t0.w);
                float ty = (t0.y + t1.y + t2.y + t3.y) * 0.25f;
                float tz = (t0.z + t1.z + t2.z + t3.z) * 0.25f;
                float tw = (t0.w + t1.w + t2.w + t3.w) * 0.25f;
                *(unsigned*)&lds2[row][128] = packbf2(ty, tz);
                lds2[row][130] = (short)bf1(tw);
            }
        }
    }
    __syncthreads();

    mfma_tile_and_store<NK1, LD1, BM / 16>(lds1, w1p, b_comb, out1, r0, t);
    mfma_tile_and_store<NK2, LD2, BM / 16>(lds2, w2p, b_agg, out2, r0, t);
}

// ---------------------------------------------------------------------------
extern "C" void kernel_launch(void* const* d_in, const int* in_sizes, int n_in,
                              void* d_out, int out_size, void* d_ws, size_t ws_size,
                              hipStream_t stream) {
    const float* spatial    = (const float*)d_in[0];
    const float* structural = (const float*)d_in[1];
    const int*   neighbour  = (const int*)  d_in[2];
    const float* W_agg      = (const float*)d_in[3];
    const float* b_agg      = (const float*)d_in[4];
    const float* W_comb     = (const float*)d_in[5];
    const float* b_comb     = (const float*)d_in[6];

    float* out1 = (float*)d_out;
    float* out2 = out1 + (size_t)NROWS * DOUT;

    short* w1p = (short*)d_ws;          // 57344 shorts
    short* w2p = w1p + 57344;           // 40960 shorts

    wprep<<<384, 256, 0, stream>>>(W_comb, W_agg, w1p, w2p);
    fused<<<NBLK, 256, 0, stream>>>(spatial, structural, neighbour,
                                    w1p, w2p, b_comb, b_agg, out1, out2);
}